// Round 1
// baseline (1131.498 us; speedup 1.0000x reference)
//
#include <hip/hip_runtime.h>

#define N_ 16
#define T_ 8
#define L_ 197
#define H_ 12
#define D_ 64
#define Q_ 196
#define C_ 768
#define QTILE 28

// ---------------- Stage 1: attention probabilities (mean over heads) -------
// grid (7 qi-tiles, 112 nt, 2 halves), block 256.
// A layout: [qi (196)][n*8+t (128)][ki (196)]  (per half buffer)
__global__ __launch_bounds__(256) void attn_kernel(
    const float* __restrict__ q, const float* __restrict__ k,
    float* __restrict__ A1, float* __restrict__ A2) {
  const int qt   = blockIdx.x;       // 0..6
  const int nt   = blockIdx.y;       // 0..111
  const int half = blockIdx.z;
  const int n  = nt / 7, tp = nt % 7;
  const int tq = (half == 0) ? tp + 1 : tp;   // q time index == output t slot
  const int tk = (half == 0) ? tp     : tp + 1;
  const int qi0 = qt * QTILE;

  const float* qbase = q + ((size_t)(n * T_ + tq) * L_ + 1 + qi0) * (H_ * D_);
  const float* kbase = k + ((size_t)(n * T_ + tk) * L_ + 1) * (H_ * D_);
  float* Ah = (half == 0) ? A1 : A2;

  __shared__ float qs[QTILE][D_];   // 7 KB   (q * scale)
  __shared__ float ks[D_][201];     // 51.5 KB, transposed [d][ki], pad 201

  const int tid = threadIdx.x;
  const int tx = tid & 63;          // ki lane
  const int ty = tid >> 6;          // wave id 0..3 -> qi group
  const bool v3 = (tx < 4);         // ki = tx+192 valid only for tx<4

  float accA[7][4];
  #pragma unroll
  for (int i = 0; i < 7; i++)
    #pragma unroll
    for (int j = 0; j < 4; j++) accA[i][j] = 0.f;

  for (int h = 0; h < H_; h++) {
    // stage q tile (28 rows x 64), scale folded in
    #pragma unroll
    for (int r = 0; r < 7; r++) {
      int e = tid + 256 * r;               // < 1792
      int qi = e >> 6, d = e & 63;
      qs[qi][d] = qbase[(size_t)qi * (H_ * D_) + h * D_ + d] * 0.125f;
    }
    // stage k (196 rows x 64) transposed into ks[d][ki]
    #pragma unroll
    for (int r = 0; r < 13; r++) {
      int e = tid + 256 * r;
      if (e < 3136) {                       // 196*16 float4 chunks
        int ki = e >> 4, dc = e & 15;
        const float4 v = *(const float4*)(kbase + (size_t)ki * (H_ * D_) + h * D_ + dc * 4);
        ks[dc * 4 + 0][ki] = v.x;
        ks[dc * 4 + 1][ki] = v.y;
        ks[dc * 4 + 2][ki] = v.z;
        ks[dc * 4 + 3][ki] = v.w;
      }
    }
    __syncthreads();

    float acc[7][4];
    #pragma unroll
    for (int i = 0; i < 7; i++)
      #pragma unroll
      for (int j = 0; j < 4; j++) acc[i][j] = 0.f;

    for (int d = 0; d < D_; d++) {
      float kr0 = ks[d][tx];
      float kr1 = ks[d][tx + 64];
      float kr2 = ks[d][tx + 128];
      float kr3 = v3 ? ks[d][tx + 192] : 0.f;
      #pragma unroll
      for (int i = 0; i < 7; i++) {
        float qv = qs[ty * 7 + i][d];       // wave-broadcast
        acc[i][0] += qv * kr0;
        acc[i][1] += qv * kr1;
        acc[i][2] += qv * kr2;
        acc[i][3] += qv * kr3;
      }
    }

    // softmax over ki (196) per qi, accumulate P/sum into accA
    #pragma unroll
    for (int i = 0; i < 7; i++) {
      float m = fmaxf(fmaxf(acc[i][0], acc[i][1]), acc[i][2]);
      if (v3) m = fmaxf(m, acc[i][3]);
      #pragma unroll
      for (int off = 32; off > 0; off >>= 1) m = fmaxf(m, __shfl_xor(m, off));
      float p0 = __expf(acc[i][0] - m);
      float p1 = __expf(acc[i][1] - m);
      float p2 = __expf(acc[i][2] - m);
      float p3 = v3 ? __expf(acc[i][3] - m) : 0.f;
      float s = p0 + p1 + p2 + p3;
      #pragma unroll
      for (int off = 32; off > 0; off >>= 1) s += __shfl_xor(s, off);
      float inv = 1.f / s;
      accA[i][0] += p0 * inv;
      accA[i][1] += p1 * inv;
      accA[i][2] += p2 * inv;
      accA[i][3] += p3 * inv;
    }
    __syncthreads();   // protect LDS before next head's staging
  }

  // store A * (1/12); layout [qi][n*8+tq][ki]
  const float w12 = 1.f / 12.f;
  #pragma unroll
  for (int i = 0; i < 7; i++) {
    size_t ab = ((size_t)(qi0 + ty * 7 + i) * (N_ * T_) + n * T_ + tq) * Q_;
    Ah[ab + tx]       = accA[i][0] * w12;
    Ah[ab + tx + 64]  = accA[i][1] * w12;
    Ah[ab + tx + 128] = accA[i][2] * w12;
    if (v3) Ah[ab + tx + 192] = accA[i][3] * w12;
  }
}

// ---------------- Stage 2: out[nt,q,c] = sum_k A[q,nt,k] * w[idx[q,k],c] ----
// grid (12 c-tiles, 196 qi), block 256 (tx = c/4, ty = m group)
__global__ __launch_bounds__(256) void mix_kernel(
    const float* __restrict__ A1, const float* __restrict__ A2,
    const float* __restrict__ w1, const float* __restrict__ w2,
    const int* __restrict__ idx, float* __restrict__ out) {
  const int ct = blockIdx.x;   // 0..11
  const int qi = blockIdx.y;   // 0..195
  const int tid = threadIdx.x;
  const int tx = tid & 15;     // 4 consecutive c each
  const int ty = tid >> 4;     // 0..15, m = ty + 16*i

  __shared__ float As[128][28];   // 14 KB
  __shared__ float Ws[28][64];    // 7 KB

  float acc[8][4];
  #pragma unroll
  for (int i = 0; i < 8; i++)
    #pragma unroll
    for (int j = 0; j < 4; j++) acc[i][j] = 0.f;

  for (int half = 0; half < 2; half++) {
    const float* Ah = half ? A2 : A1;
    const float* w  = half ? w2 : w1;
    for (int kc = 0; kc < 7; kc++) {
      int k0 = kc * 28;
      __syncthreads();
      // load A tile: 128 x 28 (coalesced: A row per qi is contiguous)
      #pragma unroll
      for (int r = 0; r < 14; r++) {
        int e = tid + 256 * r;            // < 3584
        int m = e / 28, kk = e - m * 28;
        As[m][kk] = Ah[((size_t)qi * (N_ * T_) + m) * Q_ + k0 + kk];
      }
      // gather W tile: 28 rows x 64 c
      #pragma unroll
      for (int r = 0; r < 7; r++) {
        int e = tid + 256 * r;            // < 1792
        int kk = e >> 6, c = e & 63;
        int wrow = idx[qi * Q_ + k0 + kk];
        Ws[kk][c] = w[(size_t)wrow * C_ + ct * 64 + c];
      }
      __syncthreads();
      #pragma unroll 4
      for (int kk = 0; kk < 28; kk++) {
        float4 wv = *(const float4*)&Ws[kk][tx * 4];
        #pragma unroll
        for (int i = 0; i < 8; i++) {
          float a = As[ty + 16 * i][kk];
          acc[i][0] += a * wv.x;
          acc[i][1] += a * wv.y;
          acc[i][2] += a * wv.z;
          acc[i][3] += a * wv.w;
        }
      }
    }
  }

  // store out[n,t,1+qi, ct*64 + tx*4 ..]
  #pragma unroll
  for (int i = 0; i < 8; i++) {
    int m = ty + 16 * i;
    float4 v = make_float4(acc[i][0], acc[i][1], acc[i][2], acc[i][3]);
    *(float4*)(out + ((size_t)m * L_ + 1 + qi) * C_ + ct * 64 + tx * 4) = v;
  }
  // zero the l=0 plane (done by qi==0 blocks, covers all c via ct)
  if (qi == 0) {
    float4 z = make_float4(0.f, 0.f, 0.f, 0.f);
    #pragma unroll
    for (int i = 0; i < 8; i++) {
      int m = ty + 16 * i;
      *(float4*)(out + (size_t)m * L_ * C_ + ct * 64 + tx * 4) = z;
    }
  }
}

extern "C" void kernel_launch(void* const* d_in, const int* in_sizes, int n_in,
                              void* d_out, int out_size, void* d_ws, size_t ws_size,
                              hipStream_t stream) {
  const float* q  = (const float*)d_in[0];
  const float* k  = (const float*)d_in[1];
  const float* w1 = (const float*)d_in[2];
  const float* w2 = (const float*)d_in[3];
  const int* idx  = (const int*)d_in[4];
  float* out = (float*)d_out;

  float* A1 = (float*)d_ws;
  size_t Aelems = (size_t)Q_ * (N_ * T_) * Q_;   // 196*128*196
  float* A2 = A1 + Aelems;

  // zero A buffers (covers the invalid t=0 / t=7 edge slots)
  hipMemsetAsync(d_ws, 0, Aelems * 2 * sizeof(float), stream);

  attn_kernel<<<dim3(7, 112, 2), 256, 0, stream>>>(q, k, A1, A2);
  mix_kernel<<<dim3(12, 196), 256, 0, stream>>>(A1, A2, w1, w2, idx, out);
}

// Round 2
// 462.430 us; speedup vs baseline: 2.4469x; 2.4469x over previous
//
#include <hip/hip_runtime.h>

#define N_ 16
#define T_ 8
#define L_ 197
#define H_ 12
#define D_ 64
#define Q_ 196
#define C_ 768
#define KP 224          // K padded for stage-2 MFMA (7 x 32)

typedef unsigned short ushort_t;
typedef __bf16 bf16x8 __attribute__((ext_vector_type(8)));
typedef float floatx4 __attribute__((ext_vector_type(4)));

static __device__ inline ushort_t f2bf(float x) {
  unsigned int u = __float_as_uint(x);
  u += 0x7fffu + ((u >> 16) & 1u);       // RNE
  return (ushort_t)(u >> 16);
}

// ---------------- Stage 1: A[qi][nt][k] = mean_h softmax_k(QK^T/8), bf16 ----
// grid (4 m-blocks, 112 nt, 2 halves), block 256 = 4 waves.
// wave w owns q-rows 64*b + 16*w .. +15; full K (208 padded) per head in LDS.
__global__ __launch_bounds__(256) void attn_kernel(
    const float* __restrict__ q, const float* __restrict__ k,
    ushort_t* __restrict__ A1, ushort_t* __restrict__ A2) {
  const int b    = blockIdx.x;       // 0..3 (q-row block of 64)
  const int nt   = blockIdx.y;       // 0..111
  const int half = blockIdx.z;
  const int n  = nt / 7, tp = nt % 7;
  const int tq = (half == 0) ? tp + 1 : tp;
  const int tk = (half == 0) ? tp     : tp + 1;
  const int ntm = n * T_ + tq;       // output (n,t) slot 0..127

  const float* qb = q + ((size_t)(n * T_ + tq) * L_ + 1) * (H_ * D_);
  const float* kb = k + ((size_t)(n * T_ + tk) * L_ + 1) * (H_ * D_);
  ushort_t* Ah = (half == 0) ? A1 : A2;

  __shared__ ushort_t qs[64][72];    // [local q-row][d], pad 72 (144B rows, 16B-aligned)
  __shared__ ushort_t ks[208][72];   // [ki][d]

  const int tid  = threadIdx.x;
  const int lane = tid & 63;
  const int wv   = tid >> 6;         // wave 0..3
  const int quad = lane >> 4;
  const int l15  = lane & 15;

  float accA[13][4];                 // mean-softmax accumulator (C/D layout)
  #pragma unroll
  for (int t = 0; t < 13; t++)
    #pragma unroll
    for (int r = 0; r < 4; r++) accA[t][r] = 0.f;

  for (int h = 0; h < H_; h++) {
    __syncthreads();
    // stage Q: 64 rows x 16 float4 chunks = 1024 -> 4/thread (scale folded)
    #pragma unroll
    for (int r = 0; r < 4; r++) {
      int e = tid + 256 * r;
      int row = e >> 4, dc = e & 15;
      int gq = 64 * b + row;
      float4 v = make_float4(0.f, 0.f, 0.f, 0.f);
      if (gq < Q_) v = *(const float4*)(qb + (size_t)gq * (H_ * D_) + h * D_ + dc * 4);
      ushort_t* dst = &qs[row][dc * 4];
      dst[0] = f2bf(v.x * 0.125f); dst[1] = f2bf(v.y * 0.125f);
      dst[2] = f2bf(v.z * 0.125f); dst[3] = f2bf(v.w * 0.125f);
    }
    // stage K: 208 rows x 16 chunks = 3328 -> 13/thread
    #pragma unroll
    for (int r = 0; r < 13; r++) {
      int e = tid + 256 * r;
      int row = e >> 4, dc = e & 15;
      float4 v = make_float4(0.f, 0.f, 0.f, 0.f);
      if (row < Q_) v = *(const float4*)(kb + (size_t)row * (H_ * D_) + h * D_ + dc * 4);
      ushort_t* dst = &ks[row][dc * 4];
      dst[0] = f2bf(v.x); dst[1] = f2bf(v.y);
      dst[2] = f2bf(v.z); dst[3] = f2bf(v.w);
    }
    __syncthreads();

    // S = Q K^T for this wave's 16 q-rows x 208 k-cols
    floatx4 S[13];
    #pragma unroll
    for (int t = 0; t < 13; t++) S[t] = (floatx4){0.f, 0.f, 0.f, 0.f};
    #pragma unroll
    for (int kk = 0; kk < 2; kk++) {
      bf16x8 a = *(const bf16x8*)&qs[16 * wv + l15][8 * quad + 32 * kk];
      #pragma unroll
      for (int t = 0; t < 13; t++) {
        bf16x8 bb = *(const bf16x8*)&ks[16 * t + l15][8 * quad + 32 * kk];
        S[t] = __builtin_amdgcn_mfma_f32_16x16x32_bf16(a, bb, S[t], 0, 0, 0);
      }
    }

    // softmax over k (196 valid) per row; accumulate P/rowsum
    #pragma unroll
    for (int r = 0; r < 4; r++) {
      float m = -1e30f;
      #pragma unroll
      for (int t = 0; t < 13; t++) {
        float v = S[t][r];
        if (t == 12 && l15 >= 4) v = -1e30f;   // mask k-pad 196..207
        m = fmaxf(m, v);
      }
      #pragma unroll
      for (int off = 1; off < 16; off <<= 1) m = fmaxf(m, __shfl_xor(m, off));
      float s = 0.f;
      #pragma unroll
      for (int t = 0; t < 13; t++) {
        float e_ = (t == 12 && l15 >= 4) ? 0.f : __expf(S[t][r] - m);
        S[t][r] = e_;
        s += e_;
      }
      #pragma unroll
      for (int off = 1; off < 16; off <<= 1) s += __shfl_xor(s, off);
      float inv = 1.f / s;
      #pragma unroll
      for (int t = 0; t < 13; t++) accA[t][r] += S[t][r] * inv;
    }
  }

  // store A * (1/12) as bf16; layout [qi][ntm][KP]
  const float s12 = 1.f / 12.f;
  #pragma unroll
  for (int t = 0; t < 13; t++)
    #pragma unroll
    for (int r = 0; r < 4; r++) {
      int qi = 64 * b + 16 * wv + 4 * quad + r;
      if (qi < Q_)
        Ah[((size_t)qi * (N_ * T_) + ntm) * KP + 16 * t + l15] = f2bf(accA[t][r] * s12);
    }
}

// ---------------- Stage 2: out[nt,qi,c] = sum_half A_h[qi] @ gather(W_h) ----
// grid (12 c-tiles of 64, 196 qi), block 256 = 4 waves; wave w -> c sub-tile 16*w.
__global__ __launch_bounds__(256) void mix_kernel(
    const ushort_t* __restrict__ A1, const ushort_t* __restrict__ A2,
    const float* __restrict__ w1, const float* __restrict__ w2,
    const int* __restrict__ idx, float* __restrict__ out) {
  const int ct = blockIdx.x;   // 0..11
  const int qi = blockIdx.y;   // 0..195
  const int tid  = threadIdx.x;
  const int lane = tid & 63;
  const int wv   = tid >> 6;
  const int quad = lane >> 4;
  const int l15  = lane & 15;

  __shared__ ushort_t As[128][40];   // [m][k-chunk 32], pad 40 (80B rows)
  __shared__ ushort_t Ws[64][40];    // [c][k-chunk 32] (B-frag layout)

  floatx4 acc[8];
  #pragma unroll
  for (int mt = 0; mt < 8; mt++) acc[mt] = (floatx4){0.f, 0.f, 0.f, 0.f};

  #pragma unroll
  for (int half = 0; half < 2; half++) {
    const ushort_t* Ah = half ? A2 : A1;
    const float* w = half ? w2 : w1;
    for (int kc = 0; kc < 7; kc++) {
      const int k0 = 32 * kc;
      __syncthreads();
      // stage A: 128 rows x 4 16B-chunks = 512 -> 2/thread
      #pragma unroll
      for (int r = 0; r < 2; r++) {
        int e = tid + 256 * r;
        int row = e >> 2, ch = e & 3;
        uint4 v = *(const uint4*)(Ah + ((size_t)qi * (N_ * T_) + row) * KP + k0 + ch * 8);
        *(uint4*)&As[row][ch * 8] = v;
      }
      // stage W gathered+transposed: 32 k-rows x 16 float4 = 512 -> 2/thread
      #pragma unroll
      for (int r = 0; r < 2; r++) {
        int e = tid + 256 * r;
        int kk = e >> 4, cc = e & 15;
        int gk = k0 + kk;
        float4 v = make_float4(0.f, 0.f, 0.f, 0.f);
        if (gk < Q_) {
          int wrow = idx[qi * Q_ + gk];
          v = *(const float4*)(w + (size_t)wrow * C_ + ct * 64 + cc * 4);
        }
        Ws[cc * 4 + 0][kk] = f2bf(v.x);
        Ws[cc * 4 + 1][kk] = f2bf(v.y);
        Ws[cc * 4 + 2][kk] = f2bf(v.z);
        Ws[cc * 4 + 3][kk] = f2bf(v.w);
      }
      __syncthreads();
      bf16x8 bb = *(const bf16x8*)&Ws[16 * wv + l15][8 * quad];
      #pragma unroll
      for (int mt = 0; mt < 8; mt++) {
        bf16x8 a = *(const bf16x8*)&As[16 * mt + l15][8 * quad];
        acc[mt] = __builtin_amdgcn_mfma_f32_16x16x32_bf16(a, bb, acc[mt], 0, 0, 0);
      }
    }
  }

  const int c = ct * 64 + 16 * wv + l15;
  #pragma unroll
  for (int mt = 0; mt < 8; mt++)
    #pragma unroll
    for (int r = 0; r < 4; r++) {
      int m = 16 * mt + 4 * quad + r;
      out[((size_t)m * L_ + 1 + qi) * C_ + c] = acc[mt][r];
    }
  if (qi == 0) {
    #pragma unroll
    for (int mt = 0; mt < 8; mt++)
      #pragma unroll
      for (int r = 0; r < 4; r++) {
        int m = 16 * mt + 4 * quad + r;
        out[(size_t)m * L_ * C_ + c] = 0.f;
      }
  }
}

extern "C" void kernel_launch(void* const* d_in, const int* in_sizes, int n_in,
                              void* d_out, int out_size, void* d_ws, size_t ws_size,
                              hipStream_t stream) {
  const float* q  = (const float*)d_in[0];
  const float* k  = (const float*)d_in[1];
  const float* w1 = (const float*)d_in[2];
  const float* w2 = (const float*)d_in[3];
  const int* idx  = (const int*)d_in[4];
  float* out = (float*)d_out;

  ushort_t* A1 = (ushort_t*)d_ws;
  size_t Aelems = (size_t)Q_ * (N_ * T_) * KP;   // 196*128*224
  ushort_t* A2 = A1 + Aelems;

  // zero A buffers: covers k-pad cols and the empty t=0 (half0) / t=7 (half1) slots
  hipMemsetAsync(d_ws, 0, Aelems * 2 * sizeof(ushort_t), stream);

  attn_kernel<<<dim3(4, 112, 2), 256, 0, stream>>>(q, k, A1, A2);
  mix_kernel<<<dim3(12, Q_), 256, 0, stream>>>(A1, A2, w1, w2, idx, out);
}